// Round 1
// baseline (408.870 us; speedup 1.0000x reference)
//
#include <hip/hip_runtime.h>
#include <cstdint>

#define NANCHOR 33600
#define BATCH   8
#define MGT     32
#define NCLS    80

// ---------------------------------------------------------------------------
// Anchor geometry: levels are [160x160 stride 8 | 80x80 stride 16 | 40x40 stride 32]
// p layout per level: [B, 144, H, W]; channel stride = H*W; anchor n = y*W + x.
// ---------------------------------------------------------------------------
struct AInfo {
    const float* ch0;   // &p_level[b][0][n]  (add c*hw for channel c)
    int   hw;
    float apx, apy, st;
};

__device__ __forceinline__ AInfo anchor_info(const float* p0, const float* p1,
                                             const float* p2, int b, int n) {
    AInfo r;
    if (n < 25600) {
        int nn = n;
        r.ch0 = p0 + (size_t)b * (144 * 25600) + nn;
        r.hw = 25600; r.st = 8.f;
        r.apx = (float)(nn % 160) + 0.5f;
        r.apy = (float)(nn / 160) + 0.5f;
    } else if (n < 32000) {
        int nn = n - 25600;
        r.ch0 = p1 + (size_t)b * (144 * 6400) + nn;
        r.hw = 6400; r.st = 16.f;
        r.apx = (float)(nn % 80) + 0.5f;
        r.apy = (float)(nn / 80) + 0.5f;
    } else {
        int nn = n - 32000;
        r.ch0 = p2 + (size_t)b * (144 * 1600) + nn;
        r.hw = 1600; r.st = 32.f;
        r.apx = (float)(nn % 40) + 0.5f;
        r.apy = (float)(nn / 40) + 0.5f;
    }
    return r;
}

__device__ __forceinline__ float ciou_f(float b1x1, float b1y1, float b1x2, float b1y2,
                                        float g1x, float g1y, float g2x, float g2y) {
    const float eps = 1e-7f;
    float w1 = b1x2 - b1x1, h1 = b1y2 - b1y1;
    float w2 = g2x - g1x,   h2 = g2y - g1y;
    float iw = fminf(b1x2, g2x) - fmaxf(b1x1, g1x);
    float ih = fminf(b1y2, g2y) - fmaxf(b1y1, g1y);
    float inter = fmaxf(iw, 0.f) * fmaxf(ih, 0.f);
    float uni = w1 * h1 + w2 * h2 - inter + eps;
    float iou = inter / uni;
    float cw = fmaxf(b1x2, g2x) - fminf(b1x1, g1x);
    float ch = fmaxf(b1y2, g2y) - fminf(b1y1, g1y);
    float c2 = cw * cw + ch * ch + eps;
    float dx = g1x + g2x - b1x1 - b1x2;
    float dy = g1y + g2y - b1y1 - b1y2;
    float rho2 = (dx * dx + dy * dy) * 0.25f;
    float t = atanf(w2 / (h2 + eps)) - atanf(w1 / (h1 + eps));
    float v = 0.40528473456935108577f * t * t;          // 4/pi^2
    float alpha = v / (v - iou + (1.f + eps));
    return iou - (rho2 / c2 + v * alpha);
}

// ---------------------------------------------------------------------------
// ws layout:
//   best : unsigned long long [B*N]   packed (score_bits<<32)|(31-m); 0 == no fg
//   pb   : float4 [B*N]               decoded pred boxes (image units, xyxy)
//   acc  : float [8*8]                per image: {softplus_sum, box, dfl, clspos, numfg}
// ---------------------------------------------------------------------------

__global__ void k_init(unsigned long long* best, float* acc) {
    int i = blockIdx.x * blockDim.x + threadIdx.x;
    if (i < BATCH * NANCHOR) best[i] = 0ull;
    if (i < 64) acc[i] = 0.f;
}

__global__ __launch_bounds__(256) void k_decode(const float* __restrict__ p0,
                                                const float* __restrict__ p1,
                                                const float* __restrict__ p2,
                                                float4* __restrict__ pb,
                                                float* __restrict__ acc) {
    int tid = blockIdx.x * blockDim.x + threadIdx.x;   // exactly B*N threads
    int b = tid / NANCHOR, n = tid % NANCHOR;
    AInfo ai = anchor_info(p0, p1, p2, b, n);

    float d[4];
#pragma unroll
    for (int k = 0; k < 4; k++) {
        float v[16];
        float mx = -1e30f;
#pragma unroll
        for (int r = 0; r < 16; r++) {
            v[r] = ai.ch0[(k * 16 + r) * ai.hw];
            mx = fmaxf(mx, v[r]);
        }
        float s = 0.f, sw = 0.f;
#pragma unroll
        for (int r = 0; r < 16; r++) {
            float e = expf(v[r] - mx);
            s += e;
            sw += e * (float)r;
        }
        d[k] = sw / s;
    }
    float x1 = (ai.apx - d[0]) * ai.st;
    float y1 = (ai.apy - d[1]) * ai.st;
    float x2 = (ai.apx + d[2]) * ai.st;
    float y2 = (ai.apy + d[3]) * ai.st;
    pb[tid] = make_float4(x1, y1, x2, y2);

    // cls negative part: sum softplus(pc) over 80 classes (fg-independent)
    float sp = 0.f;
#pragma unroll 4
    for (int c = 0; c < NCLS; c++) {
        float x = ai.ch0[(64 + c) * ai.hw];
        sp += fmaxf(x, 0.f) + log1pf(expf(-fabsf(x)));
    }
    // wave(64) reduce — N divisible by 64, so a wave never straddles images
#pragma unroll
    for (int o = 32; o > 0; o >>= 1) sp += __shfl_down(sp, o, 64);
    if ((threadIdx.x & 63) == 0) atomicAdd(&acc[b * 8 + 0], sp);
}

__global__ __launch_bounds__(256) void k_assign(const float* __restrict__ p0,
                                                const float* __restrict__ p1,
                                                const float* __restrict__ p2,
                                                const float4* __restrict__ pb,
                                                const float* __restrict__ gtb,
                                                const int* __restrict__ gtl,
                                                unsigned long long* __restrict__ best) {
    int bm = blockIdx.x;          // 256 blocks: one per (b, m)
    int b = bm >> 5, m = bm & 31;
    const float* g = gtb + (size_t)(b * MGT + m) * 4;
    float g0 = g[0], g1 = g[1], g2 = g[2], g3 = g[3];
    int label = gtl[b * MGT + m];
    int tid = threadIdx.x;

    float tv[10];
    int   ti[10];
#pragma unroll
    for (int j = 0; j < 10; j++) { tv[j] = -1.f; ti[j] = 0x7fffffff; }
    float maxu = 0.f;   // max over UNMASKED align (pre iou>0.1 filter)

    for (int n = tid; n < NANCHOR; n += 256) {
        AInfo ai = anchor_info(p0, p1, p2, b, n);
        float ax = ai.apx * ai.st, ay = ai.apy * ai.st;
        if (ax < g0 || ax > g2 || ay < g1 || ay > g3) continue;   // in_gt == 0 -> align 0
        float4 box = pb[b * NANCHOR + n];
        float c = ciou_f(box.x, box.y, box.z, box.w, g0, g1, g2, g3);
        float iou = fmaxf(c, 0.f);
        if (iou <= 0.f) continue;                                  // align 0
        float pcv = ai.ch0[(64 + label) * ai.hw];
        float ps = 1.f / (1.f + expf(-pcv));
        float i2 = iou * iou;
        float a = ps * i2 * i2 * i2;                               // ps^1 * iou^6
        maxu = fmaxf(maxu, a);
        if (iou > 0.1f && a > tv[9]) {
            // insert; strict > keeps earlier (lower n) ahead on ties == top_k stability
            tv[9] = a; ti[9] = n;
#pragma unroll
            for (int j = 9; j > 0; --j) {
                if (tv[j] > tv[j - 1]) {
                    float tf = tv[j]; tv[j] = tv[j - 1]; tv[j - 1] = tf;
                    int   tt = ti[j]; ti[j] = ti[j - 1]; ti[j - 1] = tt;
                }
            }
        }
    }

    __shared__ float sval[2560];
    __shared__ int   sidx[2560];
    __shared__ float rv[256];
    __shared__ int   ra[256];
    __shared__ int   rs[256];
    __shared__ float smax[256];

#pragma unroll
    for (int j = 0; j < 10; j++) {
        sval[tid * 10 + j] = tv[j];
        sidx[tid * 10 + j] = ti[j];
    }
    smax[tid] = maxu;
    __syncthreads();
    for (int s = 128; s > 0; s >>= 1) {
        if (tid < s) smax[tid] = fmaxf(smax[tid], smax[tid + s]);
        __syncthreads();
    }
    float denom = smax[0] + 1e-9f;

    // 10 rounds of block argmax (value desc, anchor idx asc) over 2560 candidates
    for (int r = 0; r < 10; r++) {
        float bv = -1.f; int ba = 0x7fffffff; int bs = -1;
#pragma unroll
        for (int j = 0; j < 10; j++) {
            int s0 = tid * 10 + j;
            float v = sval[s0]; int a0 = sidx[s0];
            if (v > bv || (v == bv && a0 < ba)) { bv = v; ba = a0; bs = s0; }
        }
        rv[tid] = bv; ra[tid] = ba; rs[tid] = bs;
        __syncthreads();
        for (int s = 128; s > 0; s >>= 1) {
            if (tid < s) {
                if (rv[tid + s] > rv[tid] ||
                    (rv[tid + s] == rv[tid] && ra[tid + s] < ra[tid])) {
                    rv[tid] = rv[tid + s]; ra[tid] = ra[tid + s]; rs[tid] = rs[tid + s];
                }
            }
            __syncthreads();
        }
        if (tid == 0 && rv[0] > 0.f) {
            float nv = rv[0] / denom;                 // normalized score in (0, 1]
            unsigned long long pk =
                ((unsigned long long)__float_as_uint(nv) << 32) |
                (unsigned long long)(31 - m);         // ties -> lower m wins (argmax-first)
            atomicMax(&best[(size_t)b * NANCHOR + ra[0]], pk);
            sval[rs[0]] = -1.f;
        }
        __syncthreads();
    }
}

__global__ __launch_bounds__(256) void k_final(const float* __restrict__ p0,
                                               const float* __restrict__ p1,
                                               const float* __restrict__ p2,
                                               const float4* __restrict__ pb,
                                               const float* __restrict__ gtb,
                                               const int* __restrict__ gtl,
                                               const unsigned long long* __restrict__ best,
                                               float* __restrict__ acc) {
    int tid = blockIdx.x * blockDim.x + threadIdx.x;
    int b = tid / NANCHOR, n = tid % NANCHOR;
    unsigned long long pk = best[tid];
    unsigned int hi = (unsigned int)(pk >> 32);
    if (hi == 0u) return;                 // not foreground
    float score = __uint_as_float(hi);
    int m = 31 - (int)(pk & 0xffffffffull);
    const float* g = gtb + (size_t)(b * MGT + m) * 4;
    float g0 = g[0], g1 = g[1], g2 = g[2], g3 = g[3];
    int label = gtl[b * MGT + m];
    float4 box = pb[tid];
    float c = ciou_f(box.x, box.y, box.z, box.w, g0, g1, g2, g3);

    AInfo ai = anchor_info(p0, p1, p2, b, n);
    float inv_st = 1.f / ai.st;           // exact (power of two)
    float t4[4] = { ai.apx - g0 * inv_st, ai.apy - g1 * inv_st,
                    g2 * inv_st - ai.apx, g3 * inv_st - ai.apy };
    float dfl = 0.f;
#pragma unroll
    for (int k = 0; k < 4; k++) {
        float t = fminf(fmaxf(t4[k], 0.f), 14.99f);   // box2dist clamp (2nd clip is no-op)
        int left = (int)floorf(t);
        int right = (left + 1 < 15) ? left + 1 : 15;
        float wl = (float)right - t;
        float wr = t - (float)left;
        float v[16];
        float mx = -1e30f;
#pragma unroll
        for (int r = 0; r < 16; r++) {
            v[r] = ai.ch0[(k * 16 + r) * ai.hw];
            mx = fmaxf(mx, v[r]);
        }
        float s = 0.f;
#pragma unroll
        for (int r = 0; r < 16; r++) s += expf(v[r] - mx);
        float lse = mx + logf(s);
        dfl += (lse - v[left]) * wl + (lse - v[right]) * wr;
    }
    float pcv = ai.ch0[(64 + label) * ai.hw];

    atomicAdd(&acc[b * 8 + 1], 1.f - c);       // box: (1 - ciou)
    atomicAdd(&acc[b * 8 + 2], dfl);           // dfl: sum over 4 sides
    atomicAdd(&acc[b * 8 + 3], pcv * score);   // cls positive term
    atomicAdd(&acc[b * 8 + 4], 1.f);           // num_fg
}

__global__ void k_combine(const float* __restrict__ acc, float* __restrict__ out) {
    if (blockIdx.x == 0 && threadIdx.x == 0) {
        float total = 0.f;
        for (int b = 0; b < BATCH; b++) {
            float nfr = acc[b * 8 + 4];
            float has = nfr > 0.f ? 1.f : 0.f;
            float nf = fmaxf(nfr, 1.f);
            float box_l = acc[b * 8 + 1] / nf;
            float cls_l = (acc[b * 8 + 0] - acc[b * 8 + 3]) / (float)NANCHOR;
            float dfl_l = acc[b * 8 + 2] / (nf * 4.f);
            total += has * (7.5f * box_l + 0.5f * cls_l + 1.5f * dfl_l);
        }
        out[0] = total;
    }
}

extern "C" void kernel_launch(void* const* d_in, const int* in_sizes, int n_in,
                              void* d_out, int out_size, void* d_ws, size_t ws_size,
                              hipStream_t stream) {
    (void)in_sizes; (void)n_in; (void)out_size; (void)ws_size;
    const float* p0  = (const float*)d_in[0];
    const float* p1  = (const float*)d_in[1];
    const float* p2  = (const float*)d_in[2];
    const float* gtb = (const float*)d_in[3];
    const int*   gtl = (const int*)d_in[4];
    // d_in[5] = strides (8,16,32) — hardcoded in anchor_info

    char* ws = (char*)d_ws;
    unsigned long long* best = (unsigned long long*)ws;                       // 2.15 MB
    float4* pb = (float4*)(ws + (size_t)BATCH * NANCHOR * 8);                 // 4.30 MB
    float*  acc = (float*)(ws + (size_t)BATCH * NANCHOR * 8
                              + (size_t)BATCH * NANCHOR * 16);                // 256 B

    const int BN = BATCH * NANCHOR;   // 268800 = 1050 * 256
    k_init   <<<(BN + 255) / 256, 256, 0, stream>>>(best, acc);
    k_decode <<<BN / 256, 256, 0, stream>>>(p0, p1, p2, pb, acc);
    k_assign <<<BATCH * MGT, 256, 0, stream>>>(p0, p1, p2, pb, gtb, gtl, best);
    k_final  <<<BN / 256, 256, 0, stream>>>(p0, p1, p2, pb, gtb, gtl, best, acc);
    k_combine<<<1, 64, 0, stream>>>(acc, (float*)d_out);
}

// Round 2
// 363.246 us; speedup vs baseline: 1.1256x; 1.1256x over previous
//
#include <hip/hip_runtime.h>
#include <cstdint>

#define NANCHOR 33600
#define BATCH   8
#define MGT     32
#define NCLS    80

// ---------------------------------------------------------------------------
// Anchor geometry: levels are [160x160 stride 8 | 80x80 stride 16 | 40x40 stride 32]
// p layout per level: [B, 144, H, W]; channel stride = H*W; anchor n = y*W + x.
// ---------------------------------------------------------------------------
struct AInfo {
    const float* ch0;   // &p_level[b][0][n]  (add c*hw for channel c)
    int   hw;
    float apx, apy, st;
};

__device__ __forceinline__ AInfo anchor_info(const float* p0, const float* p1,
                                             const float* p2, int b, int n) {
    AInfo r;
    if (n < 25600) {
        int nn = n;
        r.ch0 = p0 + (size_t)b * (144 * 25600) + nn;
        r.hw = 25600; r.st = 8.f;
        r.apx = (float)(nn % 160) + 0.5f;
        r.apy = (float)(nn / 160) + 0.5f;
    } else if (n < 32000) {
        int nn = n - 25600;
        r.ch0 = p1 + (size_t)b * (144 * 6400) + nn;
        r.hw = 6400; r.st = 16.f;
        r.apx = (float)(nn % 80) + 0.5f;
        r.apy = (float)(nn / 80) + 0.5f;
    } else {
        int nn = n - 32000;
        r.ch0 = p2 + (size_t)b * (144 * 1600) + nn;
        r.hw = 1600; r.st = 32.f;
        r.apx = (float)(nn % 40) + 0.5f;
        r.apy = (float)(nn / 40) + 0.5f;
    }
    return r;
}

__device__ __forceinline__ float ciou_f(float b1x1, float b1y1, float b1x2, float b1y2,
                                        float g1x, float g1y, float g2x, float g2y) {
    const float eps = 1e-7f;
    float w1 = b1x2 - b1x1, h1 = b1y2 - b1y1;
    float w2 = g2x - g1x,   h2 = g2y - g1y;
    float iw = fminf(b1x2, g2x) - fmaxf(b1x1, g1x);
    float ih = fminf(b1y2, g2y) - fmaxf(b1y1, g1y);
    float inter = fmaxf(iw, 0.f) * fmaxf(ih, 0.f);
    float uni = w1 * h1 + w2 * h2 - inter + eps;
    float iou = inter / uni;
    float cw = fmaxf(b1x2, g2x) - fminf(b1x1, g1x);
    float ch = fmaxf(b1y2, g2y) - fminf(b1y1, g1y);
    float c2 = cw * cw + ch * ch + eps;
    float dx = g1x + g2x - b1x1 - b1x2;
    float dy = g1y + g2y - b1y1 - b1y2;
    float rho2 = (dx * dx + dy * dy) * 0.25f;
    float t = atanf(w2 / (h2 + eps)) - atanf(w1 / (h1 + eps));
    float v = 0.40528473456935108577f * t * t;          // 4/pi^2
    float alpha = v / (v - iou + (1.f + eps));
    return iou - (rho2 / c2 + v * alpha);
}

__device__ __forceinline__ float4 max4(float4 a, float4 b) {
    return make_float4(fmaxf(a.x, b.x), fmaxf(a.y, b.y), fmaxf(a.z, b.z), fmaxf(a.w, b.w));
}
__device__ __forceinline__ float fast_splus(float x) {
    // softplus = max(x,0) + log(1 + e^{-|x|}) via native v_exp/v_log
    return fmaxf(x, 0.f) + __logf(1.f + __expf(-fabsf(x)));
}

// ---------------------------------------------------------------------------
// ws layout:
//   best : unsigned long long [B*N]   packed (score_bits<<32)|(31-m); 0 == no fg
//   pb   : float4 [B*N]               decoded pred boxes (image units, xyxy)
//   acc  : float [8*8]                per image: {softplus_sum, box, dfl, clspos, numfg}
// ---------------------------------------------------------------------------

__global__ void k_init(ulonglong2* best2, float* acc) {
    int i = blockIdx.x * blockDim.x + threadIdx.x;
    if (i < BATCH * NANCHOR / 2) best2[i] = make_ulonglong2(0ull, 0ull);
    if (i < 64) acc[i] = 0.f;
}

// One thread = 4 consecutive anchors (same image, same level, same row).
// Grid: (33, BATCH); block 256; guard t < 8400.
__global__ __launch_bounds__(256) void k_decode(const float* __restrict__ p0,
                                                const float* __restrict__ p1,
                                                const float* __restrict__ p2,
                                                float4* __restrict__ pb,
                                                float* __restrict__ acc) {
    int b = blockIdx.y;
    int t = blockIdx.x * blockDim.x + threadIdx.x;   // anchor-group index in image
    float sp = 0.f;
    if (t < NANCHOR / 4) {
        int n = t * 4;
        const float* ch0; int hw; float st, apx, apy;
        if (n < 25600) {
            ch0 = p0 + (size_t)b * (144 * 25600) + n;
            hw = 25600; st = 8.f;
            apx = (float)(n % 160) + 0.5f; apy = (float)(n / 160) + 0.5f;
        } else if (n < 32000) {
            int nn = n - 25600;
            ch0 = p1 + (size_t)b * (144 * 6400) + nn;
            hw = 6400; st = 16.f;
            apx = (float)(nn % 80) + 0.5f; apy = (float)(nn / 80) + 0.5f;
        } else {
            int nn = n - 32000;
            ch0 = p2 + (size_t)b * (144 * 1600) + nn;
            hw = 1600; st = 32.f;
            apx = (float)(nn % 40) + 0.5f; apy = (float)(nn / 40) + 0.5f;
        }

        float d[4][4];   // [k][anchor]
#pragma unroll
        for (int k = 0; k < 4; k++) {
            float4 v[16];
#pragma unroll
            for (int r = 0; r < 16; r++)
                v[r] = *(const float4*)(ch0 + (size_t)(k * 16 + r) * hw);
            float4 mx = v[0];
#pragma unroll
            for (int r = 1; r < 16; r++) mx = max4(mx, v[r]);
            float4 s  = make_float4(0.f, 0.f, 0.f, 0.f);
            float4 sw = make_float4(0.f, 0.f, 0.f, 0.f);
#pragma unroll
            for (int r = 0; r < 16; r++) {
                float fr = (float)r;
                float ex = __expf(v[r].x - mx.x);
                float ey = __expf(v[r].y - mx.y);
                float ez = __expf(v[r].z - mx.z);
                float ew = __expf(v[r].w - mx.w);
                s.x += ex; s.y += ey; s.z += ez; s.w += ew;
                sw.x += ex * fr; sw.y += ey * fr; sw.z += ez * fr; sw.w += ew * fr;
            }
            d[k][0] = sw.x / s.x; d[k][1] = sw.y / s.y;
            d[k][2] = sw.z / s.z; d[k][3] = sw.w / s.w;
        }
        float4* pbase = pb + (size_t)b * NANCHOR + n;
#pragma unroll
        for (int i = 0; i < 4; i++) {
            float ax = apx + (float)i;
            pbase[i] = make_float4((ax - d[0][i]) * st, (apy - d[1][i]) * st,
                                   (ax + d[2][i]) * st, (apy + d[3][i]) * st);
        }

        // cls negative part: sum softplus over 80 classes x 4 anchors
#pragma unroll 4
        for (int c = 0; c < NCLS; c++) {
            float4 x = *(const float4*)(ch0 + (size_t)(64 + c) * hw);
            sp += fast_splus(x.x) + fast_splus(x.y) + fast_splus(x.z) + fast_splus(x.w);
        }
    }
    // block is single-image (grid.y = b), so wave reduce is safe
#pragma unroll
    for (int o = 32; o > 0; o >>= 1) sp += __shfl_down(sp, o, 64);
    if ((threadIdx.x & 63) == 0) atomicAdd(&acc[b * 8 + 0], sp);
}

__global__ __launch_bounds__(256) void k_assign(const float* __restrict__ p0,
                                                const float* __restrict__ p1,
                                                const float* __restrict__ p2,
                                                const float4* __restrict__ pb,
                                                const float* __restrict__ gtb,
                                                const int* __restrict__ gtl,
                                                unsigned long long* __restrict__ best) {
    int bm = blockIdx.x;          // 256 blocks: one per (b, m)
    int b = bm >> 5, m = bm & 31;
    const float* g = gtb + (size_t)(b * MGT + m) * 4;
    float g0 = g[0], g1 = g[1], g2 = g[2], g3 = g[3];
    int label = gtl[b * MGT + m];
    int tid = threadIdx.x;

    float tv[10];
    int   ti[10];
#pragma unroll
    for (int j = 0; j < 10; j++) { tv[j] = -1.f; ti[j] = 0x7fffffff; }
    float maxu = 0.f;   // max over UNMASKED align (pre iou>0.1 filter)

    for (int n = tid; n < NANCHOR; n += 256) {
        AInfo ai = anchor_info(p0, p1, p2, b, n);
        float ax = ai.apx * ai.st, ay = ai.apy * ai.st;
        if (ax < g0 || ax > g2 || ay < g1 || ay > g3) continue;   // in_gt == 0 -> align 0
        float4 box = pb[b * NANCHOR + n];
        float c = ciou_f(box.x, box.y, box.z, box.w, g0, g1, g2, g3);
        float iou = fmaxf(c, 0.f);
        if (iou <= 0.f) continue;                                  // align 0
        float pcv = ai.ch0[(size_t)(64 + label) * ai.hw];
        float ps = 1.f / (1.f + __expf(-pcv));
        float i2 = iou * iou;
        float a = ps * i2 * i2 * i2;                               // ps^1 * iou^6
        maxu = fmaxf(maxu, a);
        if (iou > 0.1f && a > tv[9]) {
            // insert; strict > keeps earlier (lower n) ahead on ties == top_k stability
            tv[9] = a; ti[9] = n;
#pragma unroll
            for (int j = 9; j > 0; --j) {
                if (tv[j] > tv[j - 1]) {
                    float tf = tv[j]; tv[j] = tv[j - 1]; tv[j - 1] = tf;
                    int   tt = ti[j]; ti[j] = ti[j - 1]; ti[j - 1] = tt;
                }
            }
        }
    }

    __shared__ float sval[2560];
    __shared__ int   sidx[2560];
    __shared__ float rv[256];
    __shared__ int   ra[256];
    __shared__ int   rs[256];
    __shared__ float smax[256];

#pragma unroll
    for (int j = 0; j < 10; j++) {
        sval[tid * 10 + j] = tv[j];
        sidx[tid * 10 + j] = ti[j];
    }
    smax[tid] = maxu;
    __syncthreads();
    for (int s = 128; s > 0; s >>= 1) {
        if (tid < s) smax[tid] = fmaxf(smax[tid], smax[tid + s]);
        __syncthreads();
    }
    float denom = smax[0] + 1e-9f;

    // 10 rounds of block argmax (value desc, anchor idx asc) over 2560 candidates
    for (int r = 0; r < 10; r++) {
        float bv = -1.f; int ba = 0x7fffffff; int bs = -1;
#pragma unroll
        for (int j = 0; j < 10; j++) {
            int s0 = tid * 10 + j;
            float v = sval[s0]; int a0 = sidx[s0];
            if (v > bv || (v == bv && a0 < ba)) { bv = v; ba = a0; bs = s0; }
        }
        rv[tid] = bv; ra[tid] = ba; rs[tid] = bs;
        __syncthreads();
        for (int s = 128; s > 0; s >>= 1) {
            if (tid < s) {
                if (rv[tid + s] > rv[tid] ||
                    (rv[tid + s] == rv[tid] && ra[tid + s] < ra[tid])) {
                    rv[tid] = rv[tid + s]; ra[tid] = ra[tid + s]; rs[tid] = rs[tid + s];
                }
            }
            __syncthreads();
        }
        if (tid == 0 && rv[0] > 0.f) {
            float nv = rv[0] / denom;                 // normalized score in (0, 1]
            unsigned long long pk =
                ((unsigned long long)__float_as_uint(nv) << 32) |
                (unsigned long long)(31 - m);         // ties -> lower m wins (argmax-first)
            atomicMax(&best[(size_t)b * NANCHOR + ra[0]], pk);
            sval[rs[0]] = -1.f;
        }
        __syncthreads();
    }
}

__global__ __launch_bounds__(256) void k_final(const float* __restrict__ p0,
                                               const float* __restrict__ p1,
                                               const float* __restrict__ p2,
                                               const float4* __restrict__ pb,
                                               const float* __restrict__ gtb,
                                               const int* __restrict__ gtl,
                                               const unsigned long long* __restrict__ best,
                                               float* __restrict__ acc) {
    int tid = blockIdx.x * blockDim.x + threadIdx.x;
    int b = tid / NANCHOR, n = tid % NANCHOR;
    unsigned long long pk = best[tid];
    unsigned int hi = (unsigned int)(pk >> 32);
    if (hi == 0u) return;                 // not foreground
    float score = __uint_as_float(hi);
    int m = 31 - (int)(pk & 0xffffffffull);
    const float* g = gtb + (size_t)(b * MGT + m) * 4;
    float g0 = g[0], g1 = g[1], g2 = g[2], g3 = g[3];
    int label = gtl[b * MGT + m];
    float4 box = pb[tid];
    float c = ciou_f(box.x, box.y, box.z, box.w, g0, g1, g2, g3);

    AInfo ai = anchor_info(p0, p1, p2, b, n);
    float inv_st = 1.f / ai.st;           // exact (power of two)
    float t4[4] = { ai.apx - g0 * inv_st, ai.apy - g1 * inv_st,
                    g2 * inv_st - ai.apx, g3 * inv_st - ai.apy };
    float dfl = 0.f;
#pragma unroll
    for (int k = 0; k < 4; k++) {
        float t = fminf(fmaxf(t4[k], 0.f), 14.99f);   // box2dist clamp (2nd clip is no-op)
        int left = (int)floorf(t);
        int right = (left + 1 < 15) ? left + 1 : 15;
        float wl = (float)right - t;
        float wr = t - (float)left;
        float v[16];
        float mx = -1e30f;
#pragma unroll
        for (int r = 0; r < 16; r++) {
            v[r] = ai.ch0[(size_t)(k * 16 + r) * ai.hw];
            mx = fmaxf(mx, v[r]);
        }
        float s = 0.f;
#pragma unroll
        for (int r = 0; r < 16; r++) s += expf(v[r] - mx);
        float lse = mx + logf(s);
        dfl += (lse - v[left]) * wl + (lse - v[right]) * wr;
    }
    float pcv = ai.ch0[(size_t)(64 + label) * ai.hw];

    atomicAdd(&acc[b * 8 + 1], 1.f - c);       // box: (1 - ciou)
    atomicAdd(&acc[b * 8 + 2], dfl);           // dfl: sum over 4 sides
    atomicAdd(&acc[b * 8 + 3], pcv * score);   // cls positive term
    atomicAdd(&acc[b * 8 + 4], 1.f);           // num_fg
}

__global__ void k_combine(const float* __restrict__ acc, float* __restrict__ out) {
    if (blockIdx.x == 0 && threadIdx.x == 0) {
        float total = 0.f;
        for (int b = 0; b < BATCH; b++) {
            float nfr = acc[b * 8 + 4];
            float has = nfr > 0.f ? 1.f : 0.f;
            float nf = fmaxf(nfr, 1.f);
            float box_l = acc[b * 8 + 1] / nf;
            float cls_l = (acc[b * 8 + 0] - acc[b * 8 + 3]) / (float)NANCHOR;
            float dfl_l = acc[b * 8 + 2] / (nf * 4.f);
            total += has * (7.5f * box_l + 0.5f * cls_l + 1.5f * dfl_l);
        }
        out[0] = total;
    }
}

extern "C" void kernel_launch(void* const* d_in, const int* in_sizes, int n_in,
                              void* d_out, int out_size, void* d_ws, size_t ws_size,
                              hipStream_t stream) {
    (void)in_sizes; (void)n_in; (void)out_size; (void)ws_size;
    const float* p0  = (const float*)d_in[0];
    const float* p1  = (const float*)d_in[1];
    const float* p2  = (const float*)d_in[2];
    const float* gtb = (const float*)d_in[3];
    const int*   gtl = (const int*)d_in[4];
    // d_in[5] = strides (8,16,32) — hardcoded in anchor_info

    char* ws = (char*)d_ws;
    unsigned long long* best = (unsigned long long*)ws;                       // 2.15 MB
    float4* pb = (float4*)(ws + (size_t)BATCH * NANCHOR * 8);                 // 4.30 MB
    float*  acc = (float*)(ws + (size_t)BATCH * NANCHOR * 8
                              + (size_t)BATCH * NANCHOR * 16);                // 256 B

    const int BN = BATCH * NANCHOR;   // 268800
    k_init   <<<(BN / 2 + 255) / 256, 256, 0, stream>>>((ulonglong2*)best, acc);
    k_decode <<<dim3((NANCHOR / 4 + 255) / 256, BATCH), 256, 0, stream>>>(p0, p1, p2, pb, acc);
    k_assign <<<BATCH * MGT, 256, 0, stream>>>(p0, p1, p2, pb, gtb, gtl, best);
    k_final  <<<BN / 256, 256, 0, stream>>>(p0, p1, p2, pb, gtb, gtl, best, acc);
    k_combine<<<1, 64, 0, stream>>>(acc, (float*)d_out);
}